// Round 9
// baseline (586.297 us; speedup 1.0000x reference)
//
#include <hip/hip_runtime.h>
#include <math.h>

#define NN 50000
#define NE 800000
#define NG 512
#define FIN 9
#define D1 64
#define D2 32
#define PAD 64  // max degree slot; deg ~ Poisson(16), P(deg>=64) ~ 1e-20
#define NN2 (2 * NN)

typedef unsigned long long ull;

static inline int cdiv(int a, int b) { return (a + b - 1) / b; }

// ---- LL build with packed (src,next): one 8B line per edge for the walk ----
__global__ void k_build(const int* __restrict__ ei, const int* __restrict__ adj,
                        int* __restrict__ head_e, ull* __restrict__ pack_e,
                        int* __restrict__ head_a, ull* __restrict__ pack_a) {
  int e = blockIdx.x * blockDim.x + threadIdx.x;
  if (e < NE) {
    int s = ei[e], d = ei[NE + e];
    int nx = atomicExch(&head_e[d], e);
    pack_e[e] = ((ull)(unsigned)s << 32) | (unsigned)nx;
    s = adj[e];
    d = adj[NE + e];
    nx = atomicExch(&head_a[d], e);
    pack_a[e] = ((ull)(unsigned)s << 32) | (unsigned)nx;
  }
}

// ---- LL -> padded slots + deg, one chain walk, one 8B load per edge ----
__global__ void k_convert(const int* __restrict__ head_e, const ull* __restrict__ pack_e,
                          const int* __restrict__ head_a, const ull* __restrict__ pack_a,
                          int* __restrict__ deg_e, int* __restrict__ slot_e,
                          int* __restrict__ deg_a, int* __restrict__ slot_a) {
  int t = blockIdx.x * blockDim.x + threadIdx.x;
  if (t >= NN2) return;
  bool isE = t < NN;
  int i = isE ? t : t - NN;
  int e = isE ? head_e[i] : head_a[i];
  const ull* pk = isE ? pack_e : pack_a;
  int* slot = (isE ? slot_e : slot_a) + (size_t)i * PAD;
  int p = 0;
  while (e >= 0 && p < PAD) {
    ull v = pk[e];
    slot[p++] = (int)(v >> 32);
    e = (int)(unsigned)(v & 0xffffffffu);
  }
  (isE ? deg_e : deg_a)[i] = p;
}

// ---- xws1 = (x @ W1) * rsqrt(1+deg); also writes dis. Wave per node, lane=feature ----
__global__ void k_xw1(const float* __restrict__ x, const float* __restrict__ W1,
                      const int* __restrict__ deg_e, float* __restrict__ dis,
                      float* __restrict__ xws1) {
  int gid = blockIdx.x * blockDim.x + threadIdx.x;
  int i = gid >> 6, j = gid & 63;
  if (i >= NN) return;
  float di = rsqrtf(1.0f + (float)deg_e[i]);
  if (j == 0) dis[i] = di;
  const float* xr = x + i * FIN;
  float acc = 0.f;
#pragma unroll
  for (int k = 0; k < FIN; ++k) acc += xr[k] * W1[k * D1 + j];
  xws1[i * D1 + j] = acc * di;
}

// ============================================================================
// Register-tiled fp32 GEMM: C[NN, FOT] = H[NN, FI] @ Wcat[FI, FOT]
// MODE 0: plain W [FI][FOT] -> OA[n*FOT+j]
// MODE 1: Wcat = [eW[:FI] | eW[FI:]] -> A=OA[n*FO+j], B=OB[n*FO+j-FO]
// SCALE: multiply output row n by dis[n]
// ============================================================================
template <int FI, int FOT, int MODE, bool SCALE>
__global__ __launch_bounds__(256) void k_gemm(const float* __restrict__ H,
                                              const float* __restrict__ W,
                                              const float* __restrict__ dis,
                                              float* __restrict__ OA,
                                              float* __restrict__ OB) {
  constexpr int TM = 4;
  constexpr int TN = (FOT >= 64) ? 4 : 2;
  constexpr int BN = 1024 * TN / FOT;
  constexpr int LDH = BN + 1;
  constexpr int FO = FOT / 2;
  __shared__ float ht[FI][LDH];
  __shared__ float wc[FI][FOT];

  for (int t = threadIdx.x; t < FI * FOT; t += 256) {
    int k = t / FOT, j = t % FOT;
    float v;
    if (MODE == 1)
      v = (j < FO) ? W[k * FO + j] : W[(FI + k) * FO + (j - FO)];
    else
      v = W[k * FOT + j];
    wc[k][j] = v;
  }
  int node0 = blockIdx.x * BN;
  for (int t = threadIdx.x; t < BN * FI; t += 256) {
    int n = t / FI, k = t % FI;
    int nn = node0 + n;
    ht[k][n] = (nn < NN) ? H[(size_t)nn * FI + k] : 0.f;
  }
  __syncthreads();

  int tn = threadIdx.x % (FOT / TN);
  int tm = threadIdx.x / (FOT / TN);
  int j0 = tn * TN, n0 = tm * TM;

  float acc[TM][TN];
#pragma unroll
  for (int m = 0; m < TM; ++m)
#pragma unroll
    for (int q = 0; q < TN; ++q) acc[m][q] = 0.f;

  for (int k = 0; k < FI; ++k) {
    float wv[TN];
    if (TN == 4) {
      float4 w4 = *(const float4*)&wc[k][j0];
      wv[0] = w4.x; wv[1] = w4.y; wv[2] = w4.z; wv[3] = w4.w;
    } else {
      float2 w2 = *(const float2*)&wc[k][j0];
      wv[0] = w2.x; wv[1] = w2.y;
    }
    float hv[TM];
#pragma unroll
    for (int m = 0; m < TM; ++m) hv[m] = ht[k][n0 + m];
#pragma unroll
    for (int m = 0; m < TM; ++m)
#pragma unroll
      for (int q = 0; q < TN; ++q) acc[m][q] += hv[m] * wv[q];
  }

#pragma unroll
  for (int m = 0; m < TM; ++m) {
    int n = node0 + n0 + m;
    if (n >= NN) break;
    float sc = SCALE ? dis[n] : 1.0f;
    float* dst;
    if (MODE == 1)
      dst = (j0 < FO) ? (OA + (size_t)n * FO + j0) : (OB + (size_t)n * FO + (j0 - FO));
    else
      dst = OA + (size_t)n * FOT + j0;
    if (TN == 4) {
      float4 o = {acc[m][0] * sc, acc[m][1] * sc, acc[m][2] * sc, acc[m][3] * sc};
      *(float4*)dst = o;
    } else {
      float2 o = {acc[m][0] * sc, acc[m][1] * sc};
      *(float2*)dst = o;
    }
  }
}

// ============================================================================
// XCD-sliced gathers: block bid handles feature slice (bid % NS) only.
// Default dispatch round-robins bid%8 across the 8 XCDs, so each XCD's L2
// touches only 50000 * (32B) = 1.6MB of the feature table -> L2-resident.
// LS = float4 lanes per node per slice; NB = nodes per block.
// ============================================================================

// ---- GCN aggregate: out = relu(b + dis[i]*(xws[i] + sum_src xws[src])) ----
template <int F, int NS>
__global__ void k_gcn4s(const float4* __restrict__ xws, const float* __restrict__ dis,
                        const int* __restrict__ deg, const int* __restrict__ slots,
                        const float* __restrict__ b, float4* __restrict__ hout) {
  constexpr int L = F / 4;
  constexpr int LS = L / NS;
  constexpr int NB = 256 / LS;
  int slice = blockIdx.x % NS;
  int chunk = blockIdx.x / NS;
  int i = chunk * NB + threadIdx.x / LS;
  if (i >= NN) return;
  int l = slice * LS + threadIdx.x % LS;
  const int* s = slots + (size_t)i * PAD;
  int n = deg[i];
  float4 acc = xws[(size_t)i * L + l];
  int t = 0;
  for (; t + 7 < n; t += 8) {
    int i0 = s[t], i1 = s[t + 1], i2 = s[t + 2], i3 = s[t + 3];
    int i4 = s[t + 4], i5 = s[t + 5], i6 = s[t + 6], i7 = s[t + 7];
    float4 v0 = xws[(size_t)i0 * L + l];
    float4 v1 = xws[(size_t)i1 * L + l];
    float4 v2 = xws[(size_t)i2 * L + l];
    float4 v3 = xws[(size_t)i3 * L + l];
    float4 v4 = xws[(size_t)i4 * L + l];
    float4 v5 = xws[(size_t)i5 * L + l];
    float4 v6 = xws[(size_t)i6 * L + l];
    float4 v7 = xws[(size_t)i7 * L + l];
    acc.x += ((v0.x + v1.x) + (v2.x + v3.x)) + ((v4.x + v5.x) + (v6.x + v7.x));
    acc.y += ((v0.y + v1.y) + (v2.y + v3.y)) + ((v4.y + v5.y) + (v6.y + v7.y));
    acc.z += ((v0.z + v1.z) + (v2.z + v3.z)) + ((v4.z + v5.z) + (v6.z + v7.z));
    acc.w += ((v0.w + v1.w) + (v2.w + v3.w)) + ((v4.w + v5.w) + (v6.w + v7.w));
  }
  for (; t < n; ++t) {
    float4 v = xws[(size_t)s[t] * L + l];
    acc.x += v.x; acc.y += v.y; acc.z += v.z; acc.w += v.w;
  }
  float di = dis[i];
  float4 bb = ((const float4*)b)[l];
  float4 o;
  o.x = fmaxf(bb.x + di * acc.x, 0.f);
  o.y = fmaxf(bb.y + di * acc.y, 0.f);
  o.z = fmaxf(bb.z + di * acc.z, 0.f);
  o.w = fmaxf(bb.w + di * acc.w, 0.f);
  hout[(size_t)i * L + l] = o;
}

// ---- EdgeConv aggregate: out = relu(A[i]-B[i]+eb + max_src B[src]) ----
template <int F, int NS>
__global__ void k_edge4s(const float4* __restrict__ A, const float4* __restrict__ B,
                         const float* __restrict__ eb, const int* __restrict__ deg,
                         const int* __restrict__ slots, float4* __restrict__ hout) {
  constexpr int L = F / 4;
  constexpr int LS = L / NS;
  constexpr int NB = 256 / LS;
  int slice = blockIdx.x % NS;
  int chunk = blockIdx.x / NS;
  int i = chunk * NB + threadIdx.x / LS;
  if (i >= NN) return;
  int l = slice * LS + threadIdx.x % LS;
  const int* s = slots + (size_t)i * PAD;
  int n = deg[i];
  float4 M = {-INFINITY, -INFINITY, -INFINITY, -INFINITY};
  int t = 0;
  for (; t + 7 < n; t += 8) {
    int i0 = s[t], i1 = s[t + 1], i2 = s[t + 2], i3 = s[t + 3];
    int i4 = s[t + 4], i5 = s[t + 5], i6 = s[t + 6], i7 = s[t + 7];
    float4 v0 = B[(size_t)i0 * L + l];
    float4 v1 = B[(size_t)i1 * L + l];
    float4 v2 = B[(size_t)i2 * L + l];
    float4 v3 = B[(size_t)i3 * L + l];
    float4 v4 = B[(size_t)i4 * L + l];
    float4 v5 = B[(size_t)i5 * L + l];
    float4 v6 = B[(size_t)i6 * L + l];
    float4 v7 = B[(size_t)i7 * L + l];
    M.x = fmaxf(M.x, fmaxf(fmaxf(fmaxf(v0.x, v1.x), fmaxf(v2.x, v3.x)),
                           fmaxf(fmaxf(v4.x, v5.x), fmaxf(v6.x, v7.x))));
    M.y = fmaxf(M.y, fmaxf(fmaxf(fmaxf(v0.y, v1.y), fmaxf(v2.y, v3.y)),
                           fmaxf(fmaxf(v4.y, v5.y), fmaxf(v6.y, v7.y))));
    M.z = fmaxf(M.z, fmaxf(fmaxf(fmaxf(v0.z, v1.z), fmaxf(v2.z, v3.z)),
                           fmaxf(fmaxf(v4.z, v5.z), fmaxf(v6.z, v7.z))));
    M.w = fmaxf(M.w, fmaxf(fmaxf(fmaxf(v0.w, v1.w), fmaxf(v2.w, v3.w)),
                           fmaxf(fmaxf(v4.w, v5.w), fmaxf(v6.w, v7.w))));
  }
  for (; t < n; ++t) {
    float4 v = B[(size_t)s[t] * L + l];
    M.x = fmaxf(M.x, v.x); M.y = fmaxf(M.y, v.y);
    M.z = fmaxf(M.z, v.z); M.w = fmaxf(M.w, v.w);
  }
  float4 a = A[(size_t)i * L + l];
  float4 bsl = B[(size_t)i * L + l];
  float4 e4 = ((const float4*)eb)[l];
  float4 o;
  o.x = fmaxf(a.x - bsl.x + e4.x + M.x, 0.f);
  o.y = fmaxf(a.y - bsl.y + e4.y + M.y, 0.f);
  o.z = fmaxf(a.z - bsl.z + e4.z + M.z, 0.f);
  o.w = fmaxf(a.w - bsl.w + e4.w + M.w, 0.f);
  hout[(size_t)i * L + l] = o;
}

// ---- FC + segment mean-pool; batch sorted -> wave-segmented reduce ----
__global__ void k_final(const float* __restrict__ h4, const float* __restrict__ fcW,
                        const float* __restrict__ fcb, const int* __restrict__ batch,
                        float* __restrict__ sums, float* __restrict__ cnt) {
  int i = blockIdx.x * blockDim.x + threadIdx.x;
  int lane = threadIdx.x & 63;
  bool valid = (i < NN);
  float val = 0.f, c = 0.f;
  int g = -1;
  if (valid) {
    float acc = fcb[0];
#pragma unroll
    for (int k = 0; k < D2; ++k) acc += h4[(size_t)i * D2 + k] * fcW[k];
    val = acc;
    c = 1.f;
    g = batch[i];
  }
#pragma unroll
  for (int d = 1; d < 64; d <<= 1) {
    float v2 = __shfl_down(val, d);
    float c2 = __shfl_down(c, d);
    int g2 = __shfl_down(g, d);
    if (lane + d < 64 && g2 == g) {
      val += v2;
      c += c2;
    }
  }
  int gprev = __shfl_up(g, 1);
  bool is_head = (lane == 0) || (gprev != g);
  if (valid && is_head) {
    atomicAdd(&sums[g], val);
    atomicAdd(&cnt[g], c);
  }
}

__global__ void k_out(const float* __restrict__ sums, const float* __restrict__ cnt,
                      float* __restrict__ out) {
  int g = blockIdx.x * blockDim.x + threadIdx.x;
  if (g < NG) out[g] = sums[g] / fmaxf(cnt[g], 1.0f);
}

extern "C" void kernel_launch(void* const* d_in, const int* in_sizes, int n_in,
                              void* d_out, int out_size, void* d_ws, size_t ws_size,
                              hipStream_t stream) {
  const float* x = (const float*)d_in[0];
  const int* ei = (const int*)d_in[1];
  const int* adj = (const int*)d_in[2];
  const int* batch = (const int*)d_in[3];
  const float* W1 = (const float*)d_in[4];
  const float* b1 = (const float*)d_in[5];
  const float* eW1 = (const float*)d_in[6];
  const float* eb1 = (const float*)d_in[7];
  const float* W2 = (const float*)d_in[8];
  const float* b2 = (const float*)d_in[9];
  const float* eW2 = (const float*)d_in[10];
  const float* eb2 = (const float*)d_in[11];
  const float* fcW = (const float*)d_in[12];
  const float* fcb = (const float*)d_in[13];
  float* out = (float*)d_out;

  // ---- workspace bump allocator ----
  char* ws = (char*)d_ws;
  size_t p = 0;
  auto alloc = [&](size_t bytes) -> void* {
    void* r = ws + p;
    p = (p + bytes + 255) & ~(size_t)255;
    return r;
  };
  // region A: init 0xFF (heads = -1)
  int* head_e = (int*)alloc(NN * 4);
  int* head_a = (int*)alloc(NN * 4);
  size_t ff_bytes = p;
  // region B: init 0 (pool accumulators)
  float* sums = (float*)alloc(NG * 4);
  float* cnt = (float*)alloc(NG * 4);
  size_t zero_end = p;
  // rest: no init
  ull* pack_e = (ull*)alloc((size_t)NE * 8);
  ull* pack_a = (ull*)alloc((size_t)NE * 8);
  int* deg_e = (int*)alloc(NN * 4);
  int* deg_a = (int*)alloc(NN * 4);
  int* slot_e = (int*)alloc((size_t)NN * PAD * 4);  // 12.8 MB
  int* slot_a = (int*)alloc((size_t)NN * PAD * 4);  // 12.8 MB
  float* dis = (float*)alloc(NN * 4);
  float* buf0 = (float*)alloc((size_t)NN * D1 * 4);  // xws1 -> h2
  float* buf1 = (float*)alloc((size_t)NN * D1 * 4);  // h1 -> xws2 -> h4
  float* buf2 = (float*)alloc((size_t)NN * D1 * 4);  // A1 -> A2|B2
  float* buf3 = (float*)alloc((size_t)NN * D1 * 4);  // B1 -> h3

  hipMemsetAsync(d_ws, 0xFF, ff_bytes, stream);
  hipMemsetAsync(ws + ff_bytes, 0, zero_end - ff_bytes, stream);

  // CSR build: packed LL exchange + single-walk convert to padded slots
  k_build<<<cdiv(NE, 256), 256, 0, stream>>>(ei, adj, head_e, pack_e, head_a, pack_a);
  k_convert<<<cdiv(NN2, 256), 256, 0, stream>>>(head_e, pack_e, head_a, pack_a,
                                                deg_e, slot_e, deg_a, slot_a);

  const int G64 = 8 * cdiv(NN, 128);  // F=64: NS=8, LS=2, 128 nodes/block
  const int G32 = 4 * cdiv(NN, 128);  // F=32: NS=4, LS=2, 128 nodes/block

  // layer 1: GCN(9->64) + relu
  k_xw1<<<cdiv(NN * D1, 256), 256, 0, stream>>>(x, W1, deg_e, dis, buf0);
  k_gcn4s<D1, 8><<<G64, 256, 0, stream>>>(
      (const float4*)buf0, dis, deg_e, slot_e, b1, (float4*)buf1);

  // layer 2: EdgeConv(64->64)
  k_gemm<D1, 2 * D1, 1, false><<<cdiv(NN, 32), 256, 0, stream>>>(buf1, eW1, nullptr, buf2, buf3);
  k_edge4s<D1, 8><<<G64, 256, 0, stream>>>(
      (const float4*)buf2, (const float4*)buf3, eb1, deg_a, slot_a, (float4*)buf0);

  // layer 3: GCN(64->32) + relu
  k_gemm<D1, D2, 0, true><<<cdiv(NN, 64), 256, 0, stream>>>(buf0, W2, dis, buf1, nullptr);
  k_gcn4s<D2, 4><<<G32, 256, 0, stream>>>(
      (const float4*)buf1, dis, deg_e, slot_e, b2, (float4*)buf3);

  // layer 4: EdgeConv(32->32)
  float* A2 = buf2;
  float* B2 = buf2 + (size_t)NN * D2;
  k_gemm<D2, 2 * D2, 1, false><<<cdiv(NN, 64), 256, 0, stream>>>(buf3, eW2, nullptr, A2, B2);
  k_edge4s<D2, 4><<<G32, 256, 0, stream>>>(
      (const float4*)A2, (const float4*)B2, eb2, deg_a, slot_a, (float4*)buf1);

  // FC + mean pool
  k_final<<<cdiv(NN, 256), 256, 0, stream>>>(buf1, fcW, fcb, batch, sums, cnt);
  k_out<<<cdiv(NG, 256), 256, 0, stream>>>(sums, cnt, out);
}

// Round 11
// 427.220 us; speedup vs baseline: 1.3724x; 1.3724x over previous
//
#include <hip/hip_runtime.h>
#include <math.h>

#define NN 50000
#define NE 800000
#define NG 512
#define FIN 9
#define D1 64
#define D2 32
#define NN2 (2 * NN)
#define NBK 4      // source buckets (partition = 12500 rows)
#define BSZ 12500  // bucket width in node ids
#define B4 24      // slots per bucket; deg/bucket ~ Poisson(4), P(>=25) ~ 1e-12
#define SLOTN (NBK * B4)

typedef unsigned long long ull;

static inline int cdiv(int a, int b) { return (a + b - 1) / b; }

// ---- LL build with packed (src,next): one 8B load per edge in the walk ----
__global__ void k_build(const int* __restrict__ ei, const int* __restrict__ adj,
                        int* __restrict__ head_e, ull* __restrict__ pack_e,
                        int* __restrict__ head_a, ull* __restrict__ pack_a) {
  int e = blockIdx.x * blockDim.x + threadIdx.x;
  if (e < NE) {
    int s = ei[e], d = ei[NE + e];
    int nx = atomicExch(&head_e[d], e);
    pack_e[e] = ((ull)(unsigned)s << 32) | (unsigned)nx;
    s = adj[e];
    d = adj[NE + e];
    nx = atomicExch(&head_a[d], e);
    pack_a[e] = ((ull)(unsigned)s << 32) | (unsigned)nx;
  }
}

// ---- LL -> bucketed padded slots (planar [bucket][node][B4]) + counts + dis ----
__global__ void k_convert(const int* __restrict__ head_e, const ull* __restrict__ pack_e,
                          const int* __restrict__ head_a, const ull* __restrict__ pack_a,
                          int4* __restrict__ bcnt_e, int* __restrict__ slot_e,
                          int4* __restrict__ bcnt_a, int* __restrict__ slot_a,
                          float* __restrict__ dis) {
  int t = blockIdx.x * blockDim.x + threadIdx.x;
  if (t >= NN2) return;
  bool isE = t < NN;
  int i = isE ? t : t - NN;
  int e = isE ? head_e[i] : head_a[i];
  const ull* pk = isE ? pack_e : pack_a;
  int* slot = isE ? slot_e : slot_a;
  int c0 = 0, c1 = 0, c2 = 0, c3 = 0, deg = 0;
  while (e >= 0) {
    ull v = pk[e];
    int s = (int)(v >> 32);
    e = (int)(unsigned)(v & 0xffffffffu);
    ++deg;
    int b = s / BSZ;  // 0..3
    if (b == 0) {
      if (c0 < B4) slot[(size_t)0 * NN * B4 + (size_t)i * B4 + c0++] = s;
    } else if (b == 1) {
      if (c1 < B4) slot[(size_t)1 * NN * B4 + (size_t)i * B4 + c1++] = s;
    } else if (b == 2) {
      if (c2 < B4) slot[(size_t)2 * NN * B4 + (size_t)i * B4 + c2++] = s;
    } else {
      if (c3 < B4) slot[(size_t)3 * NN * B4 + (size_t)i * B4 + c3++] = s;
    }
  }
  (isE ? bcnt_e : bcnt_a)[i] = make_int4(c0, c1, c2, c3);
  if (isE) dis[i] = rsqrtf(1.0f + (float)deg);
}

// ---- xws1 = (x @ W1) * dis. Wave per node, lane = feature ----
__global__ void k_xw1(const float* __restrict__ x, const float* __restrict__ W1,
                      const float* __restrict__ dis, float* __restrict__ xws1) {
  int gid = blockIdx.x * blockDim.x + threadIdx.x;
  int i = gid >> 6, j = gid & 63;
  if (i >= NN) return;
  const float* xr = x + i * FIN;
  float acc = 0.f;
#pragma unroll
  for (int k = 0; k < FIN; ++k) acc += xr[k] * W1[k * D1 + j];
  xws1[i * D1 + j] = acc * dis[i];
}

// ============================================================================
// Register-tiled fp32 GEMM (unchanged)
// ============================================================================
template <int FI, int FOT, int MODE, bool SCALE>
__global__ __launch_bounds__(256) void k_gemm(const float* __restrict__ H,
                                              const float* __restrict__ W,
                                              const float* __restrict__ dis,
                                              float* __restrict__ OA,
                                              float* __restrict__ OB) {
  constexpr int TM = 4;
  constexpr int TN = (FOT >= 64) ? 4 : 2;
  constexpr int BN = 1024 * TN / FOT;
  constexpr int LDH = BN + 1;
  constexpr int FO = FOT / 2;
  __shared__ float ht[FI][LDH];
  __shared__ float wc[FI][FOT];

  for (int t = threadIdx.x; t < FI * FOT; t += 256) {
    int k = t / FOT, j = t % FOT;
    float v;
    if (MODE == 1)
      v = (j < FO) ? W[k * FO + j] : W[(FI + k) * FO + (j - FO)];
    else
      v = W[k * FOT + j];
    wc[k][j] = v;
  }
  int node0 = blockIdx.x * BN;
  for (int t = threadIdx.x; t < BN * FI; t += 256) {
    int n = t / FI, k = t % FI;
    int nn = node0 + n;
    ht[k][n] = (nn < NN) ? H[(size_t)nn * FI + k] : 0.f;
  }
  __syncthreads();

  int tn = threadIdx.x % (FOT / TN);
  int tm = threadIdx.x / (FOT / TN);
  int j0 = tn * TN, n0 = tm * TM;

  float acc[TM][TN];
#pragma unroll
  for (int m = 0; m < TM; ++m)
#pragma unroll
    for (int q = 0; q < TN; ++q) acc[m][q] = 0.f;

  for (int k = 0; k < FI; ++k) {
    float wv[TN];
    if (TN == 4) {
      float4 w4 = *(const float4*)&wc[k][j0];
      wv[0] = w4.x; wv[1] = w4.y; wv[2] = w4.z; wv[3] = w4.w;
    } else {
      float2 w2 = *(const float2*)&wc[k][j0];
      wv[0] = w2.x; wv[1] = w2.y;
    }
    float hv[TM];
#pragma unroll
    for (int m = 0; m < TM; ++m) hv[m] = ht[k][n0 + m];
#pragma unroll
    for (int m = 0; m < TM; ++m)
#pragma unroll
      for (int q = 0; q < TN; ++q) acc[m][q] += hv[m] * wv[q];
  }

#pragma unroll
  for (int m = 0; m < TM; ++m) {
    int n = node0 + n0 + m;
    if (n >= NN) break;
    float sc = SCALE ? dis[n] : 1.0f;
    float* dst;
    if (MODE == 1)
      dst = (j0 < FO) ? (OA + (size_t)n * FO + j0) : (OB + (size_t)n * FO + (j0 - FO));
    else
      dst = OA + (size_t)n * FOT + j0;
    if (TN == 4) {
      float4 o = {acc[m][0] * sc, acc[m][1] * sc, acc[m][2] * sc, acc[m][3] * sc};
      *(float4*)dst = o;
    } else {
      float2 o = {acc[m][0] * sc, acc[m][1] * sc};
      *(float2*)dst = o;
    }
  }
}

// ============================================================================
// Bucketed multi-pass gathers. Each launch processes buckets [blo,bhi);
// ALL blocks read only that 3.2MB source partition -> L2-resident on every
// XCD (no dispatch-mapping assumption). flags: 1=init, 2=finalize.
// ============================================================================

// ---- GCN sum pass: final = relu(bias + dis*(self + sum)) ----
template <int F>
__global__ void k_gcnp(const float4* __restrict__ xws, const float* __restrict__ dis,
                       const int4* __restrict__ bcnt, const int* __restrict__ slots,
                       const float* __restrict__ bias, float4* __restrict__ outb,
                       int blo, int bhi, int flags) {
  constexpr int L = F / 4;
  int gid = blockIdx.x * blockDim.x + threadIdx.x;
  int i = gid / L, l = gid % L;
  if (i >= NN) return;
  int4 bc = bcnt[i];
  float4 acc = (flags & 1) ? xws[(size_t)i * L + l] : outb[(size_t)i * L + l];
  for (int b = blo; b < bhi; ++b) {
    int n = (b == 0) ? bc.x : (b == 1) ? bc.y : (b == 2) ? bc.z : bc.w;
    const int* sb = slots + (size_t)b * NN * B4 + (size_t)i * B4;
    int t = 0;
    for (; t + 3 < n; t += 4) {
      int i0 = sb[t], i1 = sb[t + 1], i2 = sb[t + 2], i3 = sb[t + 3];
      float4 v0 = xws[(size_t)i0 * L + l];
      float4 v1 = xws[(size_t)i1 * L + l];
      float4 v2 = xws[(size_t)i2 * L + l];
      float4 v3 = xws[(size_t)i3 * L + l];
      acc.x += (v0.x + v1.x) + (v2.x + v3.x);
      acc.y += (v0.y + v1.y) + (v2.y + v3.y);
      acc.z += (v0.z + v1.z) + (v2.z + v3.z);
      acc.w += (v0.w + v1.w) + (v2.w + v3.w);
    }
    for (; t < n; ++t) {
      float4 v = xws[(size_t)sb[t] * L + l];
      acc.x += v.x; acc.y += v.y; acc.z += v.z; acc.w += v.w;
    }
  }
  if (flags & 2) {
    float di = dis[i];
    float4 bb = ((const float4*)bias)[l];
    float4 o;
    o.x = fmaxf(bb.x + di * acc.x, 0.f);
    o.y = fmaxf(bb.y + di * acc.y, 0.f);
    o.z = fmaxf(bb.z + di * acc.z, 0.f);
    o.w = fmaxf(bb.w + di * acc.w, 0.f);
    outb[(size_t)i * L + l] = o;
  } else {
    outb[(size_t)i * L + l] = acc;
  }
}

// ---- EdgeConv max pass: final = relu(A - B + eb + M); empty -> -inf -> 0 ----
template <int F>
__global__ void k_edgep(const float4* __restrict__ A, const float4* __restrict__ B,
                        const float* __restrict__ eb, const int4* __restrict__ bcnt,
                        const int* __restrict__ slots, float4* __restrict__ outb,
                        int blo, int bhi, int flags) {
  constexpr int L = F / 4;
  int gid = blockIdx.x * blockDim.x + threadIdx.x;
  int i = gid / L, l = gid % L;
  if (i >= NN) return;
  int4 bc = bcnt[i];
  float4 M;
  if (flags & 1) {
    M.x = -INFINITY; M.y = -INFINITY; M.z = -INFINITY; M.w = -INFINITY;
  } else {
    M = outb[(size_t)i * L + l];
  }
  for (int b = blo; b < bhi; ++b) {
    int n = (b == 0) ? bc.x : (b == 1) ? bc.y : (b == 2) ? bc.z : bc.w;
    const int* sb = slots + (size_t)b * NN * B4 + (size_t)i * B4;
    int t = 0;
    for (; t + 3 < n; t += 4) {
      int i0 = sb[t], i1 = sb[t + 1], i2 = sb[t + 2], i3 = sb[t + 3];
      float4 v0 = B[(size_t)i0 * L + l];
      float4 v1 = B[(size_t)i1 * L + l];
      float4 v2 = B[(size_t)i2 * L + l];
      float4 v3 = B[(size_t)i3 * L + l];
      M.x = fmaxf(M.x, fmaxf(fmaxf(v0.x, v1.x), fmaxf(v2.x, v3.x)));
      M.y = fmaxf(M.y, fmaxf(fmaxf(v0.y, v1.y), fmaxf(v2.y, v3.y)));
      M.z = fmaxf(M.z, fmaxf(fmaxf(v0.z, v1.z), fmaxf(v2.z, v3.z)));
      M.w = fmaxf(M.w, fmaxf(fmaxf(v0.w, v1.w), fmaxf(v2.w, v3.w)));
    }
    for (; t < n; ++t) {
      float4 v = B[(size_t)sb[t] * L + l];
      M.x = fmaxf(M.x, v.x); M.y = fmaxf(M.y, v.y);
      M.z = fmaxf(M.z, v.z); M.w = fmaxf(M.w, v.w);
    }
  }
  if (flags & 2) {
    float4 a = A[(size_t)i * L + l];
    float4 bsl = B[(size_t)i * L + l];
    float4 e4 = ((const float4*)eb)[l];
    float4 o;
    o.x = fmaxf(a.x - bsl.x + e4.x + M.x, 0.f);
    o.y = fmaxf(a.y - bsl.y + e4.y + M.y, 0.f);
    o.z = fmaxf(a.z - bsl.z + e4.z + M.z, 0.f);
    o.w = fmaxf(a.w - bsl.w + e4.w + M.w, 0.f);
    outb[(size_t)i * L + l] = o;
  } else {
    outb[(size_t)i * L + l] = M;
  }
}

// ---- FC + segment mean-pool; batch sorted -> wave-segmented reduce ----
__global__ void k_final(const float* __restrict__ h4, const float* __restrict__ fcW,
                        const float* __restrict__ fcb, const int* __restrict__ batch,
                        float* __restrict__ sums, float* __restrict__ cnt) {
  int i = blockIdx.x * blockDim.x + threadIdx.x;
  int lane = threadIdx.x & 63;
  bool valid = (i < NN);
  float val = 0.f, c = 0.f;
  int g = -1;
  if (valid) {
    float acc = fcb[0];
#pragma unroll
    for (int k = 0; k < D2; ++k) acc += h4[(size_t)i * D2 + k] * fcW[k];
    val = acc;
    c = 1.f;
    g = batch[i];
  }
#pragma unroll
  for (int d = 1; d < 64; d <<= 1) {
    float v2 = __shfl_down(val, d);
    float c2 = __shfl_down(c, d);
    int g2 = __shfl_down(g, d);
    if (lane + d < 64 && g2 == g) {
      val += v2;
      c += c2;
    }
  }
  int gprev = __shfl_up(g, 1);
  bool is_head = (lane == 0) || (gprev != g);
  if (valid && is_head) {
    atomicAdd(&sums[g], val);
    atomicAdd(&cnt[g], c);
  }
}

__global__ void k_out(const float* __restrict__ sums, const float* __restrict__ cnt,
                      float* __restrict__ out) {
  int g = blockIdx.x * blockDim.x + threadIdx.x;
  if (g < NG) out[g] = sums[g] / fmaxf(cnt[g], 1.0f);
}

extern "C" void kernel_launch(void* const* d_in, const int* in_sizes, int n_in,
                              void* d_out, int out_size, void* d_ws, size_t ws_size,
                              hipStream_t stream) {
  const float* x = (const float*)d_in[0];
  const int* ei = (const int*)d_in[1];
  const int* adj = (const int*)d_in[2];
  const int* batch = (const int*)d_in[3];
  const float* W1 = (const float*)d_in[4];
  const float* b1 = (const float*)d_in[5];
  const float* eW1 = (const float*)d_in[6];
  const float* eb1 = (const float*)d_in[7];
  const float* W2 = (const float*)d_in[8];
  const float* b2 = (const float*)d_in[9];
  const float* eW2 = (const float*)d_in[10];
  const float* eb2 = (const float*)d_in[11];
  const float* fcW = (const float*)d_in[12];
  const float* fcb = (const float*)d_in[13];
  float* out = (float*)d_out;

  // ---- workspace bump allocator ----
  char* ws = (char*)d_ws;
  size_t p = 0;
  auto alloc = [&](size_t bytes) -> void* {
    void* r = ws + p;
    p = (p + bytes + 255) & ~(size_t)255;
    return r;
  };
  // region A: init 0xFF (heads = -1)
  int* head_e = (int*)alloc(NN * 4);
  int* head_a = (int*)alloc(NN * 4);
  size_t ff_bytes = p;
  // region B: init 0 (pool accumulators)
  float* sums = (float*)alloc(NG * 4);
  float* cnt = (float*)alloc(NG * 4);
  size_t zero_end = p;
  // rest: no init
  ull* pack_e = (ull*)alloc((size_t)NE * 8);
  ull* pack_a = (ull*)alloc((size_t)NE * 8);
  int4* bcnt_e = (int4*)alloc((size_t)NN * 16);
  int4* bcnt_a = (int4*)alloc((size_t)NN * 16);
  int* slot_e = (int*)alloc((size_t)NN * SLOTN * 4);  // 19.2 MB
  int* slot_a = (int*)alloc((size_t)NN * SLOTN * 4);  // 19.2 MB
  float* dis = (float*)alloc(NN * 4);
  float* buf0 = (float*)alloc((size_t)NN * D1 * 4);  // xws1 -> h2
  float* buf1 = (float*)alloc((size_t)NN * D1 * 4);  // h1 -> xws2 -> h4
  float* buf2 = (float*)alloc((size_t)NN * D1 * 4);  // A1 -> A2|B2
  float* buf3 = (float*)alloc((size_t)NN * D1 * 4);  // B1 -> h3

  hipMemsetAsync(d_ws, 0xFF, ff_bytes, stream);
  hipMemsetAsync(ws + ff_bytes, 0, zero_end - ff_bytes, stream);

  // CSR build: packed LL exchange + single-walk bucketed convert
  k_build<<<cdiv(NE, 256), 256, 0, stream>>>(ei, adj, head_e, pack_e, head_a, pack_a);
  k_convert<<<cdiv(NN2, 256), 256, 0, stream>>>(head_e, pack_e, head_a, pack_a,
                                                bcnt_e, slot_e, bcnt_a, slot_a, dis);

  const int G64 = cdiv(NN * (D1 / 4), 256);
  const int G32 = cdiv(NN * (D2 / 4), 256);

  // layer 1: GCN(9->64) + relu — 4 bucket passes
  k_xw1<<<cdiv(NN * D1, 256), 256, 0, stream>>>(x, W1, dis, buf0);
  k_gcnp<D1><<<G64, 256, 0, stream>>>((const float4*)buf0, dis, bcnt_e, slot_e, b1,
                                      (float4*)buf1, 0, 1, 1);
  k_gcnp<D1><<<G64, 256, 0, stream>>>((const float4*)buf0, dis, bcnt_e, slot_e, b1,
                                      (float4*)buf1, 1, 2, 0);
  k_gcnp<D1><<<G64, 256, 0, stream>>>((const float4*)buf0, dis, bcnt_e, slot_e, b1,
                                      (float4*)buf1, 2, 3, 0);
  k_gcnp<D1><<<G64, 256, 0, stream>>>((const float4*)buf0, dis, bcnt_e, slot_e, b1,
                                      (float4*)buf1, 3, 4, 2);

  // layer 2: EdgeConv(64->64) — GEMM then 4 bucket passes
  k_gemm<D1, 2 * D1, 1, false><<<cdiv(NN, 32), 256, 0, stream>>>(buf1, eW1, nullptr, buf2, buf3);
  k_edgep<D1><<<G64, 256, 0, stream>>>((const float4*)buf2, (const float4*)buf3, eb1,
                                       bcnt_a, slot_a, (float4*)buf0, 0, 1, 1);
  k_edgep<D1><<<G64, 256, 0, stream>>>((const float4*)buf2, (const float4*)buf3, eb1,
                                       bcnt_a, slot_a, (float4*)buf0, 1, 2, 0);
  k_edgep<D1><<<G64, 256, 0, stream>>>((const float4*)buf2, (const float4*)buf3, eb1,
                                       bcnt_a, slot_a, (float4*)buf0, 2, 3, 0);
  k_edgep<D1><<<G64, 256, 0, stream>>>((const float4*)buf2, (const float4*)buf3, eb1,
                                       bcnt_a, slot_a, (float4*)buf0, 3, 4, 2);

  // layer 3: GCN(64->32) + relu — 2 passes (2 buckets each, same 3.2MB partitions)
  k_gemm<D1, D2, 0, true><<<cdiv(NN, 64), 256, 0, stream>>>(buf0, W2, dis, buf1, nullptr);
  k_gcnp<D2><<<G32, 256, 0, stream>>>((const float4*)buf1, dis, bcnt_e, slot_e, b2,
                                      (float4*)buf3, 0, 2, 1);
  k_gcnp<D2><<<G32, 256, 0, stream>>>((const float4*)buf1, dis, bcnt_e, slot_e, b2,
                                      (float4*)buf3, 2, 4, 2);

  // layer 4: EdgeConv(32->32) — GEMM then 2 passes
  float* A2 = buf2;
  float* B2 = buf2 + (size_t)NN * D2;
  k_gemm<D2, 2 * D2, 1, false><<<cdiv(NN, 64), 256, 0, stream>>>(buf3, eW2, nullptr, A2, B2);
  k_edgep<D2><<<G32, 256, 0, stream>>>((const float4*)A2, (const float4*)B2, eb2,
                                       bcnt_a, slot_a, (float4*)buf1, 0, 2, 1);
  k_edgep<D2><<<G32, 256, 0, stream>>>((const float4*)A2, (const float4*)B2, eb2,
                                       bcnt_a, slot_a, (float4*)buf1, 2, 4, 2);

  // FC + mean pool
  k_final<<<cdiv(NN, 256), 256, 0, stream>>>(buf1, fcW, fcb, batch, sums, cnt);
  k_out<<<cdiv(NG, 256), 256, 0, stream>>>(sums, cnt, out);
}

// Round 12
// 374.556 us; speedup vs baseline: 1.5653x; 1.1406x over previous
//
#include <hip/hip_runtime.h>
#include <math.h>

#define NN 50000
#define NE 800000
#define NG 512
#define FIN 9
#define D1 64
#define D2 32
#define PAD 64  // max degree slot; deg ~ Poisson(16), P(deg>=64) ~ 1e-20
#define NN2 (2 * NN)

typedef unsigned long long ull;

static inline int cdiv(int a, int b) { return (a + b - 1) / b; }

// ---- LL build with packed (src,next): one 8B load per edge in the walk ----
__global__ void k_build(const int* __restrict__ ei, const int* __restrict__ adj,
                        int* __restrict__ head_e, ull* __restrict__ pack_e,
                        int* __restrict__ head_a, ull* __restrict__ pack_a) {
  int e = blockIdx.x * blockDim.x + threadIdx.x;
  if (e < NE) {
    int s = ei[e], d = ei[NE + e];
    int nx = atomicExch(&head_e[d], e);
    pack_e[e] = ((ull)(unsigned)s << 32) | (unsigned)nx;
    s = adj[e];
    d = adj[NE + e];
    nx = atomicExch(&head_a[d], e);
    pack_a[e] = ((ull)(unsigned)s << 32) | (unsigned)nx;
  }
}

// ---- LL -> flat padded slots + deg + dis; one 8B random load per edge ----
__global__ void k_convert(const int* __restrict__ head_e, const ull* __restrict__ pack_e,
                          const int* __restrict__ head_a, const ull* __restrict__ pack_a,
                          int* __restrict__ deg_e, int* __restrict__ slot_e,
                          int* __restrict__ deg_a, int* __restrict__ slot_a,
                          float* __restrict__ dis) {
  int t = blockIdx.x * blockDim.x + threadIdx.x;
  if (t >= NN2) return;
  bool isE = t < NN;
  int i = isE ? t : t - NN;
  int e = isE ? head_e[i] : head_a[i];
  const ull* pk = isE ? pack_e : pack_a;
  int* slot = (isE ? slot_e : slot_a) + (size_t)i * PAD;
  int p = 0;
  while (e >= 0 && p < PAD) {
    ull v = pk[e];
    slot[p++] = (int)(v >> 32);
    e = (int)(unsigned)(v & 0xffffffffu);
  }
  (isE ? deg_e : deg_a)[i] = p;
  if (isE) dis[i] = rsqrtf(1.0f + (float)p);
}

// ---- xws1 = (x @ W1) * dis. Wave per node, lane = feature ----
__global__ void k_xw1(const float* __restrict__ x, const float* __restrict__ W1,
                      const float* __restrict__ dis, float* __restrict__ xws1) {
  int gid = blockIdx.x * blockDim.x + threadIdx.x;
  int i = gid >> 6, j = gid & 63;
  if (i >= NN) return;
  const float* xr = x + i * FIN;
  float acc = 0.f;
#pragma unroll
  for (int k = 0; k < FIN; ++k) acc += xr[k] * W1[k * D1 + j];
  xws1[i * D1 + j] = acc * dis[i];
}

// ============================================================================
// Register-tiled fp32 GEMM: C[NN, FOT] = H[NN, FI] @ Wcat[FI, FOT]
// MODE 0: plain W [FI][FOT] -> OA[n*FOT+j]
// MODE 1: Wcat = [eW[:FI] | eW[FI:]] -> A=OA[n*FO+j], B=OB[n*FO+j-FO]
// SCALE: multiply output row n by dis[n]
// ============================================================================
template <int FI, int FOT, int MODE, bool SCALE>
__global__ __launch_bounds__(256) void k_gemm(const float* __restrict__ H,
                                              const float* __restrict__ W,
                                              const float* __restrict__ dis,
                                              float* __restrict__ OA,
                                              float* __restrict__ OB) {
  constexpr int TM = 4;
  constexpr int TN = (FOT >= 64) ? 4 : 2;
  constexpr int BN = 1024 * TN / FOT;
  constexpr int LDH = BN + 1;
  constexpr int FO = FOT / 2;
  __shared__ float ht[FI][LDH];
  __shared__ float wc[FI][FOT];

  for (int t = threadIdx.x; t < FI * FOT; t += 256) {
    int k = t / FOT, j = t % FOT;
    float v;
    if (MODE == 1)
      v = (j < FO) ? W[k * FO + j] : W[(FI + k) * FO + (j - FO)];
    else
      v = W[k * FOT + j];
    wc[k][j] = v;
  }
  int node0 = blockIdx.x * BN;
  for (int t = threadIdx.x; t < BN * FI; t += 256) {
    int n = t / FI, k = t % FI;
    int nn = node0 + n;
    ht[k][n] = (nn < NN) ? H[(size_t)nn * FI + k] : 0.f;
  }
  __syncthreads();

  int tn = threadIdx.x % (FOT / TN);
  int tm = threadIdx.x / (FOT / TN);
  int j0 = tn * TN, n0 = tm * TM;

  float acc[TM][TN];
#pragma unroll
  for (int m = 0; m < TM; ++m)
#pragma unroll
    for (int q = 0; q < TN; ++q) acc[m][q] = 0.f;

  for (int k = 0; k < FI; ++k) {
    float wv[TN];
    if (TN == 4) {
      float4 w4 = *(const float4*)&wc[k][j0];
      wv[0] = w4.x; wv[1] = w4.y; wv[2] = w4.z; wv[3] = w4.w;
    } else {
      float2 w2 = *(const float2*)&wc[k][j0];
      wv[0] = w2.x; wv[1] = w2.y;
    }
    float hv[TM];
#pragma unroll
    for (int m = 0; m < TM; ++m) hv[m] = ht[k][n0 + m];
#pragma unroll
    for (int m = 0; m < TM; ++m)
#pragma unroll
      for (int q = 0; q < TN; ++q) acc[m][q] += hv[m] * wv[q];
  }

#pragma unroll
  for (int m = 0; m < TM; ++m) {
    int n = node0 + n0 + m;
    if (n >= NN) break;
    float sc = SCALE ? dis[n] : 1.0f;
    float* dst;
    if (MODE == 1)
      dst = (j0 < FO) ? (OA + (size_t)n * FO + j0) : (OB + (size_t)n * FO + (j0 - FO));
    else
      dst = OA + (size_t)n * FOT + j0;
    if (TN == 4) {
      float4 o = {acc[m][0] * sc, acc[m][1] * sc, acc[m][2] * sc, acc[m][3] * sc};
      *(float4*)dst = o;
    } else {
      float2 o = {acc[m][0] * sc, acc[m][1] * sc};
      *(float2*)dst = o;
    }
  }
}

// ---- GCN aggregate, padded CSR, float4 lanes, unroll 8:
//      out = relu(b + dis[i] * (xws[i] + sum_src xws[src])) ----
template <int F>
__global__ void k_gcn4(const float4* __restrict__ xws, const float* __restrict__ dis,
                       const int* __restrict__ deg, const int* __restrict__ slots,
                       const float* __restrict__ b, float4* __restrict__ hout) {
  constexpr int L = F / 4;
  int gid = blockIdx.x * blockDim.x + threadIdx.x;
  int i = gid / L, l = gid % L;
  if (i >= NN) return;
  const int* s = slots + (size_t)i * PAD;
  int n = deg[i];
  float4 acc = xws[(size_t)i * L + l];
  int t = 0;
  for (; t + 7 < n; t += 8) {
    int i0 = s[t], i1 = s[t + 1], i2 = s[t + 2], i3 = s[t + 3];
    int i4 = s[t + 4], i5 = s[t + 5], i6 = s[t + 6], i7 = s[t + 7];
    float4 v0 = xws[(size_t)i0 * L + l];
    float4 v1 = xws[(size_t)i1 * L + l];
    float4 v2 = xws[(size_t)i2 * L + l];
    float4 v3 = xws[(size_t)i3 * L + l];
    float4 v4 = xws[(size_t)i4 * L + l];
    float4 v5 = xws[(size_t)i5 * L + l];
    float4 v6 = xws[(size_t)i6 * L + l];
    float4 v7 = xws[(size_t)i7 * L + l];
    acc.x += ((v0.x + v1.x) + (v2.x + v3.x)) + ((v4.x + v5.x) + (v6.x + v7.x));
    acc.y += ((v0.y + v1.y) + (v2.y + v3.y)) + ((v4.y + v5.y) + (v6.y + v7.y));
    acc.z += ((v0.z + v1.z) + (v2.z + v3.z)) + ((v4.z + v5.z) + (v6.z + v7.z));
    acc.w += ((v0.w + v1.w) + (v2.w + v3.w)) + ((v4.w + v5.w) + (v6.w + v7.w));
  }
  for (; t < n; ++t) {
    float4 v = xws[(size_t)s[t] * L + l];
    acc.x += v.x; acc.y += v.y; acc.z += v.z; acc.w += v.w;
  }
  float di = dis[i];
  float4 bb = ((const float4*)b)[l];
  float4 o;
  o.x = fmaxf(bb.x + di * acc.x, 0.f);
  o.y = fmaxf(bb.y + di * acc.y, 0.f);
  o.z = fmaxf(bb.z + di * acc.z, 0.f);
  o.w = fmaxf(bb.w + di * acc.w, 0.f);
  hout[(size_t)i * L + l] = o;
}

// ---- EdgeConv aggregate, padded CSR, float4 lanes, unroll 8, relu hoisted:
//      out = relu(A[i]-B[i]+eb + max_src B[src]); empty -> -inf -> 0 ----
template <int F>
__global__ void k_edge4(const float4* __restrict__ A, const float4* __restrict__ B,
                        const float* __restrict__ eb, const int* __restrict__ deg,
                        const int* __restrict__ slots, float4* __restrict__ hout) {
  constexpr int L = F / 4;
  int gid = blockIdx.x * blockDim.x + threadIdx.x;
  int i = gid / L, l = gid % L;
  if (i >= NN) return;
  const int* s = slots + (size_t)i * PAD;
  int n = deg[i];
  float4 M = {-INFINITY, -INFINITY, -INFINITY, -INFINITY};
  int t = 0;
  for (; t + 7 < n; t += 8) {
    int i0 = s[t], i1 = s[t + 1], i2 = s[t + 2], i3 = s[t + 3];
    int i4 = s[t + 4], i5 = s[t + 5], i6 = s[t + 6], i7 = s[t + 7];
    float4 v0 = B[(size_t)i0 * L + l];
    float4 v1 = B[(size_t)i1 * L + l];
    float4 v2 = B[(size_t)i2 * L + l];
    float4 v3 = B[(size_t)i3 * L + l];
    float4 v4 = B[(size_t)i4 * L + l];
    float4 v5 = B[(size_t)i5 * L + l];
    float4 v6 = B[(size_t)i6 * L + l];
    float4 v7 = B[(size_t)i7 * L + l];
    M.x = fmaxf(M.x, fmaxf(fmaxf(fmaxf(v0.x, v1.x), fmaxf(v2.x, v3.x)),
                           fmaxf(fmaxf(v4.x, v5.x), fmaxf(v6.x, v7.x))));
    M.y = fmaxf(M.y, fmaxf(fmaxf(fmaxf(v0.y, v1.y), fmaxf(v2.y, v3.y)),
                           fmaxf(fmaxf(v4.y, v5.y), fmaxf(v6.y, v7.y))));
    M.z = fmaxf(M.z, fmaxf(fmaxf(fmaxf(v0.z, v1.z), fmaxf(v2.z, v3.z)),
                           fmaxf(fmaxf(v4.z, v5.z), fmaxf(v6.z, v7.z))));
    M.w = fmaxf(M.w, fmaxf(fmaxf(fmaxf(v0.w, v1.w), fmaxf(v2.w, v3.w)),
                           fmaxf(fmaxf(v4.w, v5.w), fmaxf(v6.w, v7.w))));
  }
  for (; t < n; ++t) {
    float4 v = B[(size_t)s[t] * L + l];
    M.x = fmaxf(M.x, v.x); M.y = fmaxf(M.y, v.y);
    M.z = fmaxf(M.z, v.z); M.w = fmaxf(M.w, v.w);
  }
  float4 a = A[(size_t)i * L + l];
  float4 bsl = B[(size_t)i * L + l];
  float4 e4 = ((const float4*)eb)[l];
  float4 o;
  o.x = fmaxf(a.x - bsl.x + e4.x + M.x, 0.f);
  o.y = fmaxf(a.y - bsl.y + e4.y + M.y, 0.f);
  o.z = fmaxf(a.z - bsl.z + e4.z + M.z, 0.f);
  o.w = fmaxf(a.w - bsl.w + e4.w + M.w, 0.f);
  hout[(size_t)i * L + l] = o;
}

// ---- FC + segment mean-pool; batch sorted -> wave-segmented reduce ----
__global__ void k_final(const float* __restrict__ h4, const float* __restrict__ fcW,
                        const float* __restrict__ fcb, const int* __restrict__ batch,
                        float* __restrict__ sums, float* __restrict__ cnt) {
  int i = blockIdx.x * blockDim.x + threadIdx.x;
  int lane = threadIdx.x & 63;
  bool valid = (i < NN);
  float val = 0.f, c = 0.f;
  int g = -1;
  if (valid) {
    float acc = fcb[0];
#pragma unroll
    for (int k = 0; k < D2; ++k) acc += h4[(size_t)i * D2 + k] * fcW[k];
    val = acc;
    c = 1.f;
    g = batch[i];
  }
#pragma unroll
  for (int d = 1; d < 64; d <<= 1) {
    float v2 = __shfl_down(val, d);
    float c2 = __shfl_down(c, d);
    int g2 = __shfl_down(g, d);
    if (lane + d < 64 && g2 == g) {
      val += v2;
      c += c2;
    }
  }
  int gprev = __shfl_up(g, 1);
  bool is_head = (lane == 0) || (gprev != g);
  if (valid && is_head) {
    atomicAdd(&sums[g], val);
    atomicAdd(&cnt[g], c);
  }
}

__global__ void k_out(const float* __restrict__ sums, const float* __restrict__ cnt,
                      float* __restrict__ out) {
  int g = blockIdx.x * blockDim.x + threadIdx.x;
  if (g < NG) out[g] = sums[g] / fmaxf(cnt[g], 1.0f);
}

extern "C" void kernel_launch(void* const* d_in, const int* in_sizes, int n_in,
                              void* d_out, int out_size, void* d_ws, size_t ws_size,
                              hipStream_t stream) {
  const float* x = (const float*)d_in[0];
  const int* ei = (const int*)d_in[1];
  const int* adj = (const int*)d_in[2];
  const int* batch = (const int*)d_in[3];
  const float* W1 = (const float*)d_in[4];
  const float* b1 = (const float*)d_in[5];
  const float* eW1 = (const float*)d_in[6];
  const float* eb1 = (const float*)d_in[7];
  const float* W2 = (const float*)d_in[8];
  const float* b2 = (const float*)d_in[9];
  const float* eW2 = (const float*)d_in[10];
  const float* eb2 = (const float*)d_in[11];
  const float* fcW = (const float*)d_in[12];
  const float* fcb = (const float*)d_in[13];
  float* out = (float*)d_out;

  // ---- workspace bump allocator ----
  char* ws = (char*)d_ws;
  size_t p = 0;
  auto alloc = [&](size_t bytes) -> void* {
    void* r = ws + p;
    p = (p + bytes + 255) & ~(size_t)255;
    return r;
  };
  // region A: init 0xFF (heads = -1)
  int* head_e = (int*)alloc(NN * 4);
  int* head_a = (int*)alloc(NN * 4);
  size_t ff_bytes = p;
  // region B: init 0 (pool accumulators)
  float* sums = (float*)alloc(NG * 4);
  float* cnt = (float*)alloc(NG * 4);
  size_t zero_end = p;
  // rest: no init
  ull* pack_e = (ull*)alloc((size_t)NE * 8);
  ull* pack_a = (ull*)alloc((size_t)NE * 8);
  int* deg_e = (int*)alloc(NN * 4);
  int* deg_a = (int*)alloc(NN * 4);
  int* slot_e = (int*)alloc((size_t)NN * PAD * 4);  // 12.8 MB
  int* slot_a = (int*)alloc((size_t)NN * PAD * 4);  // 12.8 MB
  float* dis = (float*)alloc(NN * 4);
  float* buf0 = (float*)alloc((size_t)NN * D1 * 4);  // xws1 -> h2
  float* buf1 = (float*)alloc((size_t)NN * D1 * 4);  // h1 -> xws2 -> h4
  float* buf2 = (float*)alloc((size_t)NN * D1 * 4);  // A1 -> A2|B2
  float* buf3 = (float*)alloc((size_t)NN * D1 * 4);  // B1 -> h3

  hipMemsetAsync(d_ws, 0xFF, ff_bytes, stream);
  hipMemsetAsync(ws + ff_bytes, 0, zero_end - ff_bytes, stream);

  // CSR build: packed LL exchange + single-walk convert to flat padded slots
  k_build<<<cdiv(NE, 256), 256, 0, stream>>>(ei, adj, head_e, pack_e, head_a, pack_a);
  k_convert<<<cdiv(NN2, 256), 256, 0, stream>>>(head_e, pack_e, head_a, pack_a,
                                                deg_e, slot_e, deg_a, slot_a, dis);

  // layer 1: GCN(9->64) + relu
  k_xw1<<<cdiv(NN * D1, 256), 256, 0, stream>>>(x, W1, dis, buf0);
  k_gcn4<D1><<<cdiv(NN * (D1 / 4), 256), 256, 0, stream>>>(
      (const float4*)buf0, dis, deg_e, slot_e, b1, (float4*)buf1);

  // layer 2: EdgeConv(64->64)
  k_gemm<D1, 2 * D1, 1, false><<<cdiv(NN, 32), 256, 0, stream>>>(buf1, eW1, nullptr, buf2, buf3);
  k_edge4<D1><<<cdiv(NN * (D1 / 4), 256), 256, 0, stream>>>(
      (const float4*)buf2, (const float4*)buf3, eb1, deg_a, slot_a, (float4*)buf0);

  // layer 3: GCN(64->32) + relu
  k_gemm<D1, D2, 0, true><<<cdiv(NN, 64), 256, 0, stream>>>(buf0, W2, dis, buf1, nullptr);
  k_gcn4<D2><<<cdiv(NN * (D2 / 4), 256), 256, 0, stream>>>(
      (const float4*)buf1, dis, deg_e, slot_e, b2, (float4*)buf3);

  // layer 4: EdgeConv(32->32)
  float* A2 = buf2;
  float* B2 = buf2 + (size_t)NN * D2;
  k_gemm<D2, 2 * D2, 1, false><<<cdiv(NN, 64), 256, 0, stream>>>(buf3, eW2, nullptr, A2, B2);
  k_edge4<D2><<<cdiv(NN * (D2 / 4), 256), 256, 0, stream>>>(
      (const float4*)A2, (const float4*)B2, eb2, deg_a, slot_a, (float4*)buf1);

  // FC + mean pool
  k_final<<<cdiv(NN, 256), 256, 0, stream>>>(buf1, fcW, fcb, batch, sums, cnt);
  k_out<<<cdiv(NG, 256), 256, 0, stream>>>(sums, cnt, out);
}

// Round 16
// 352.144 us; speedup vs baseline: 1.6649x; 1.0636x over previous
//
#include <hip/hip_runtime.h>
#include <math.h>

#define NN 50000
#define NE 800000
#define NG 512
#define FIN 9
#define D1 64
#define D2 32
#define PAD 64  // max degree slot; deg ~ Poisson(16), P(deg>=64) ~ 1e-20
#define NN2 (2 * NN)
#define XSP 16  // xs row padded to 16 floats (64B line)

typedef unsigned long long ull;

static inline int cdiv(int a, int b) { return (a + b - 1) / b; }

// ---- LL build with packed (src,next): one 8B load per edge in the walk ----
__global__ void k_build(const int* __restrict__ ei, const int* __restrict__ adj,
                        int* __restrict__ head_e, ull* __restrict__ pack_e,
                        int* __restrict__ head_a, ull* __restrict__ pack_a) {
  int e = blockIdx.x * blockDim.x + threadIdx.x;
  if (e < NE) {
    int s = ei[e], d = ei[NE + e];
    int nx = atomicExch(&head_e[d], e);
    pack_e[e] = ((ull)(unsigned)s << 32) | (unsigned)nx;
    s = adj[e];
    d = adj[NE + e];
    nx = atomicExch(&head_a[d], e);
    pack_a[e] = ((ull)(unsigned)s << 32) | (unsigned)nx;
  }
}

// ---- LL -> flat padded slots + deg + dis + xs (= x*dis padded to 16) ----
__global__ void k_convert(const int* __restrict__ head_e, const ull* __restrict__ pack_e,
                          const int* __restrict__ head_a, const ull* __restrict__ pack_a,
                          const float* __restrict__ x,
                          int* __restrict__ deg_e, int* __restrict__ slot_e,
                          int* __restrict__ deg_a, int* __restrict__ slot_a,
                          float* __restrict__ dis, float* __restrict__ xs) {
  int t = blockIdx.x * blockDim.x + threadIdx.x;
  if (t >= NN2) return;
  bool isE = t < NN;
  int i = isE ? t : t - NN;
  int e = isE ? head_e[i] : head_a[i];
  const ull* pk = isE ? pack_e : pack_a;
  int* slot = (isE ? slot_e : slot_a) + (size_t)i * PAD;
  int p = 0;
  while (e >= 0 && p < PAD) {
    ull v = pk[e];
    slot[p++] = (int)(v >> 32);
    e = (int)(unsigned)(v & 0xffffffffu);
  }
  (isE ? deg_e : deg_a)[i] = p;
  if (isE) {
    float di = rsqrtf(1.0f + (float)p);
    dis[i] = di;
    const float* xr = x + (size_t)i * FIN;
    float* xo = xs + (size_t)i * XSP;
#pragma unroll
    for (int k = 0; k < FIN; ++k) xo[k] = xr[k] * di;
#pragma unroll
    for (int k = FIN; k < XSP; ++k) xo[k] = 0.f;
  }
}

// ---- layer-1 pre-GEMM aggregate over 16-float padded xs rows (L2-resident):
//      g[i] = xs[i] + sum_src xs[src]; 4 lanes/node ----
__global__ void k_gagg(const float4* __restrict__ xs, const int* __restrict__ deg,
                       const int* __restrict__ slots, float4* __restrict__ g) {
  constexpr int L = XSP / 4;  // 4
  int gid = blockIdx.x * blockDim.x + threadIdx.x;
  int i = gid / L, l = gid % L;
  if (i >= NN) return;
  const int* s = slots + (size_t)i * PAD;
  int n = deg[i];
  float4 acc = xs[(size_t)i * L + l];
  int t = 0;
  for (; t + 7 < n; t += 8) {
    int i0 = s[t], i1 = s[t + 1], i2 = s[t + 2], i3 = s[t + 3];
    int i4 = s[t + 4], i5 = s[t + 5], i6 = s[t + 6], i7 = s[t + 7];
    float4 v0 = xs[(size_t)i0 * L + l];
    float4 v1 = xs[(size_t)i1 * L + l];
    float4 v2 = xs[(size_t)i2 * L + l];
    float4 v3 = xs[(size_t)i3 * L + l];
    float4 v4 = xs[(size_t)i4 * L + l];
    float4 v5 = xs[(size_t)i5 * L + l];
    float4 v6 = xs[(size_t)i6 * L + l];
    float4 v7 = xs[(size_t)i7 * L + l];
    acc.x += ((v0.x + v1.x) + (v2.x + v3.x)) + ((v4.x + v5.x) + (v6.x + v7.x));
    acc.y += ((v0.y + v1.y) + (v2.y + v3.y)) + ((v4.y + v5.y) + (v6.y + v7.y));
    acc.z += ((v0.z + v1.z) + (v2.z + v3.z)) + ((v4.z + v5.z) + (v6.z + v7.z));
    acc.w += ((v0.w + v1.w) + (v2.w + v3.w)) + ((v4.w + v5.w) + (v6.w + v7.w));
  }
  for (; t < n; ++t) {
    float4 v = xs[(size_t)s[t] * L + l];
    acc.x += v.x; acc.y += v.y; acc.z += v.z; acc.w += v.w;
  }
  g[(size_t)i * L + l] = acc;
}

// ============================================================================
// Register-tiled fp32 GEMM: C[NN, FOT] = H[NN, FI(stride LDHS)] @ Wcat[FI, FOT]
// MODE 0: plain W -> OA[n*FOT+j] (times dis if SCALE)
// MODE 1: Wcat = [eW[:FI] | eW[FI:]] -> A=OA[n*FO+j], B=OB[n*FO+j-FO]
// MODE 2: OA[n*FOT+j] = relu(bias[j] + dis[n]*acc)   (layer-1 epilogue)
// ============================================================================
template <int FI, int FOT, int MODE, bool SCALE, int LDHS>
__global__ __launch_bounds__(256) void k_gemm(const float* __restrict__ H,
                                              const float* __restrict__ W,
                                              const float* __restrict__ dis,
                                              const float* __restrict__ bias,
                                              float* __restrict__ OA,
                                              float* __restrict__ OB) {
  constexpr int TM = 4;
  constexpr int TN = (FOT >= 64) ? 4 : 2;
  constexpr int BN = 1024 * TN / FOT;
  constexpr int LDH = BN + 1;
  constexpr int FO = FOT / 2;
  __shared__ float ht[FI][LDH];
  __shared__ float wc[FI][FOT];

  for (int t = threadIdx.x; t < FI * FOT; t += 256) {
    int k = t / FOT, j = t % FOT;
    float v;
    if (MODE == 1)
      v = (j < FO) ? W[k * FO + j] : W[(FI + k) * FO + (j - FO)];
    else
      v = W[k * FOT + j];
    wc[k][j] = v;
  }
  int node0 = blockIdx.x * BN;
  for (int t = threadIdx.x; t < BN * FI; t += 256) {
    int n = t / FI, k = t % FI;
    int nn = node0 + n;
    ht[k][n] = (nn < NN) ? H[(size_t)nn * LDHS + k] : 0.f;
  }
  __syncthreads();

  int tn = threadIdx.x % (FOT / TN);
  int tm = threadIdx.x / (FOT / TN);
  int j0 = tn * TN, n0 = tm * TM;

  float acc[TM][TN];
#pragma unroll
  for (int m = 0; m < TM; ++m)
#pragma unroll
    for (int q = 0; q < TN; ++q) acc[m][q] = 0.f;

  for (int k = 0; k < FI; ++k) {
    float wv[TN];
    if (TN == 4) {
      float4 w4 = *(const float4*)&wc[k][j0];
      wv[0] = w4.x; wv[1] = w4.y; wv[2] = w4.z; wv[3] = w4.w;
    } else {
      float2 w2 = *(const float2*)&wc[k][j0];
      wv[0] = w2.x; wv[1] = w2.y;
    }
    float hv[TM];
#pragma unroll
    for (int m = 0; m < TM; ++m) hv[m] = ht[k][n0 + m];
#pragma unroll
    for (int m = 0; m < TM; ++m)
#pragma unroll
      for (int q = 0; q < TN; ++q) acc[m][q] += hv[m] * wv[q];
  }

#pragma unroll
  for (int m = 0; m < TM; ++m) {
    int n = node0 + n0 + m;
    if (n >= NN) break;
    float o[TN];
    if (MODE == 2) {
      float di = dis[n];
#pragma unroll
      for (int q = 0; q < TN; ++q) o[q] = fmaxf(bias[j0 + q] + di * acc[m][q], 0.f);
    } else {
      float sc = SCALE ? dis[n] : 1.0f;
#pragma unroll
      for (int q = 0; q < TN; ++q) o[q] = acc[m][q] * sc;
    }
    float* dst;
    if (MODE == 1)
      dst = (j0 < FO) ? (OA + (size_t)n * FO + j0) : (OB + (size_t)n * FO + (j0 - FO));
    else
      dst = OA + (size_t)n * FOT + j0;
    if (TN == 4) {
      float4 ov = {o[0], o[1], o[2], o[3]};
      *(float4*)dst = ov;
    } else {
      float2 ov = {o[0], o[1]};
      *(float2*)dst = ov;
    }
  }
}

// ---- GCN aggregate (layer 3), padded CSR, float4 lanes, unroll 8:
//      out = relu(b + dis[i] * (xws[i] + sum_src xws[src])) ----
template <int F>
__global__ void k_gcn4(const float4* __restrict__ xws, const float* __restrict__ dis,
                       const int* __restrict__ deg, const int* __restrict__ slots,
                       const float* __restrict__ b, float4* __restrict__ hout) {
  constexpr int L = F / 4;
  int gid = blockIdx.x * blockDim.x + threadIdx.x;
  int i = gid / L, l = gid % L;
  if (i >= NN) return;
  const int* s = slots + (size_t)i * PAD;
  int n = deg[i];
  float4 acc = xws[(size_t)i * L + l];
  int t = 0;
  for (; t + 7 < n; t += 8) {
    int i0 = s[t], i1 = s[t + 1], i2 = s[t + 2], i3 = s[t + 3];
    int i4 = s[t + 4], i5 = s[t + 5], i6 = s[t + 6], i7 = s[t + 7];
    float4 v0 = xws[(size_t)i0 * L + l];
    float4 v1 = xws[(size_t)i1 * L + l];
    float4 v2 = xws[(size_t)i2 * L + l];
    float4 v3 = xws[(size_t)i3 * L + l];
    float4 v4 = xws[(size_t)i4 * L + l];
    float4 v5 = xws[(size_t)i5 * L + l];
    float4 v6 = xws[(size_t)i6 * L + l];
    float4 v7 = xws[(size_t)i7 * L + l];
    acc.x += ((v0.x + v1.x) + (v2.x + v3.x)) + ((v4.x + v5.x) + (v6.x + v7.x));
    acc.y += ((v0.y + v1.y) + (v2.y + v3.y)) + ((v4.y + v5.y) + (v6.y + v7.y));
    acc.z += ((v0.z + v1.z) + (v2.z + v3.z)) + ((v4.z + v5.z) + (v6.z + v7.z));
    acc.w += ((v0.w + v1.w) + (v2.w + v3.w)) + ((v4.w + v5.w) + (v6.w + v7.w));
  }
  for (; t < n; ++t) {
    float4 v = xws[(size_t)s[t] * L + l];
    acc.x += v.x; acc.y += v.y; acc.z += v.z; acc.w += v.w;
  }
  float di = dis[i];
  float4 bb = ((const float4*)b)[l];
  float4 o;
  o.x = fmaxf(bb.x + di * acc.x, 0.f);
  o.y = fmaxf(bb.y + di * acc.y, 0.f);
  o.z = fmaxf(bb.z + di * acc.z, 0.f);
  o.w = fmaxf(bb.w + di * acc.w, 0.f);
  hout[(size_t)i * L + l] = o;
}

// ---- EdgeConv aggregate, padded CSR, float4 lanes, unroll 8, relu hoisted:
//      out = relu(A[i]-B[i]+eb + max_src B[src]); empty -> -inf -> 0 ----
template <int F>
__global__ void k_edge4(const float4* __restrict__ A, const float4* __restrict__ B,
                        const float* __restrict__ eb, const int* __restrict__ deg,
                        const int* __restrict__ slots, float4* __restrict__ hout) {
  constexpr int L = F / 4;
  int gid = blockIdx.x * blockDim.x + threadIdx.x;
  int i = gid / L, l = gid % L;
  if (i >= NN) return;
  const int* s = slots + (size_t)i * PAD;
  int n = deg[i];
  float4 M = {-INFINITY, -INFINITY, -INFINITY, -INFINITY};
  int t = 0;
  for (; t + 7 < n; t += 8) {
    int i0 = s[t], i1 = s[t + 1], i2 = s[t + 2], i3 = s[t + 3];
    int i4 = s[t + 4], i5 = s[t + 5], i6 = s[t + 6], i7 = s[t + 7];
    float4 v0 = B[(size_t)i0 * L + l];
    float4 v1 = B[(size_t)i1 * L + l];
    float4 v2 = B[(size_t)i2 * L + l];
    float4 v3 = B[(size_t)i3 * L + l];
    float4 v4 = B[(size_t)i4 * L + l];
    float4 v5 = B[(size_t)i5 * L + l];
    float4 v6 = B[(size_t)i6 * L + l];
    float4 v7 = B[(size_t)i7 * L + l];
    M.x = fmaxf(M.x, fmaxf(fmaxf(fmaxf(v0.x, v1.x), fmaxf(v2.x, v3.x)),
                           fmaxf(fmaxf(v4.x, v5.x), fmaxf(v6.x, v7.x))));
    M.y = fmaxf(M.y, fmaxf(fmaxf(fmaxf(v0.y, v1.y), fmaxf(v2.y, v3.y)),
                           fmaxf(fmaxf(v4.y, v5.y), fmaxf(v6.y, v7.y))));
    M.z = fmaxf(M.z, fmaxf(fmaxf(fmaxf(v0.z, v1.z), fmaxf(v2.z, v3.z)),
                           fmaxf(fmaxf(v4.z, v5.z), fmaxf(v6.z, v7.z))));
    M.w = fmaxf(M.w, fmaxf(fmaxf(fmaxf(v0.w, v1.w), fmaxf(v2.w, v3.w)),
                           fmaxf(fmaxf(v4.w, v5.w), fmaxf(v6.w, v7.w))));
  }
  for (; t < n; ++t) {
    float4 v = B[(size_t)s[t] * L + l];
    M.x = fmaxf(M.x, v.x); M.y = fmaxf(M.y, v.y);
    M.z = fmaxf(M.z, v.z); M.w = fmaxf(M.w, v.w);
  }
  float4 a = A[(size_t)i * L + l];
  float4 bsl = B[(size_t)i * L + l];
  float4 e4 = ((const float4*)eb)[l];
  float4 o;
  o.x = fmaxf(a.x - bsl.x + e4.x + M.x, 0.f);
  o.y = fmaxf(a.y - bsl.y + e4.y + M.y, 0.f);
  o.z = fmaxf(a.z - bsl.z + e4.z + M.z, 0.f);
  o.w = fmaxf(a.w - bsl.w + e4.w + M.w, 0.f);
  hout[(size_t)i * L + l] = o;
}

// ---- FC + segment mean-pool; batch sorted -> wave-segmented reduce ----
__global__ void k_final(const float* __restrict__ h4, const float* __restrict__ fcW,
                        const float* __restrict__ fcb, const int* __restrict__ batch,
                        float* __restrict__ sums, float* __restrict__ cnt) {
  int i = blockIdx.x * blockDim.x + threadIdx.x;
  int lane = threadIdx.x & 63;
  bool valid = (i < NN);
  float val = 0.f, c = 0.f;
  int g = -1;
  if (valid) {
    float acc = fcb[0];
#pragma unroll
    for (int k = 0; k < D2; ++k) acc += h4[(size_t)i * D2 + k] * fcW[k];
    val = acc;
    c = 1.f;
    g = batch[i];
  }
#pragma unroll
  for (int d = 1; d < 64; d <<= 1) {
    float v2 = __shfl_down(val, d);
    float c2 = __shfl_down(c, d);
    int g2 = __shfl_down(g, d);
    if (lane + d < 64 && g2 == g) {
      val += v2;
      c += c2;
    }
  }
  int gprev = __shfl_up(g, 1);
  bool is_head = (lane == 0) || (gprev != g);
  if (valid && is_head) {
    atomicAdd(&sums[g], val);
    atomicAdd(&cnt[g], c);
  }
}

__global__ void k_out(const float* __restrict__ sums, const float* __restrict__ cnt,
                      float* __restrict__ out) {
  int g = blockIdx.x * blockDim.x + threadIdx.x;
  if (g < NG) out[g] = sums[g] / fmaxf(cnt[g], 1.0f);
}

extern "C" void kernel_launch(void* const* d_in, const int* in_sizes, int n_in,
                              void* d_out, int out_size, void* d_ws, size_t ws_size,
                              hipStream_t stream) {
  const float* x = (const float*)d_in[0];
  const int* ei = (const int*)d_in[1];
  const int* adj = (const int*)d_in[2];
  const int* batch = (const int*)d_in[3];
  const float* W1 = (const float*)d_in[4];
  const float* b1 = (const float*)d_in[5];
  const float* eW1 = (const float*)d_in[6];
  const float* eb1 = (const float*)d_in[7];
  const float* W2 = (const float*)d_in[8];
  const float* b2 = (const float*)d_in[9];
  const float* eW2 = (const float*)d_in[10];
  const float* eb2 = (const float*)d_in[11];
  const float* fcW = (const float*)d_in[12];
  const float* fcb = (const float*)d_in[13];
  float* out = (float*)d_out;

  // ---- workspace bump allocator ----
  char* ws = (char*)d_ws;
  size_t p = 0;
  auto alloc = [&](size_t bytes) -> void* {
    void* r = ws + p;
    p = (p + bytes + 255) & ~(size_t)255;
    return r;
  };
  // region A: init 0xFF (heads = -1)
  int* head_e = (int*)alloc(NN * 4);
  int* head_a = (int*)alloc(NN * 4);
  size_t ff_bytes = p;
  // region B: init 0 (pool accumulators)
  float* sums = (float*)alloc(NG * 4);
  float* cnt = (float*)alloc(NG * 4);
  size_t zero_end = p;
  // rest: no init
  ull* pack_e = (ull*)alloc((size_t)NE * 8);
  ull* pack_a = (ull*)alloc((size_t)NE * 8);
  int* deg_e = (int*)alloc(NN * 4);
  int* deg_a = (int*)alloc(NN * 4);
  int* slot_e = (int*)alloc((size_t)NN * PAD * 4);  // 12.8 MB
  int* slot_a = (int*)alloc((size_t)NN * PAD * 4);  // 12.8 MB
  float* dis = (float*)alloc(NN * 4);
  float* xs = (float*)alloc((size_t)NN * XSP * 4);  // 3.2 MB (L2-resident gather table)
  float* gbuf = (float*)alloc((size_t)NN * XSP * 4);
  float* buf0 = (float*)alloc((size_t)NN * D1 * 4);  // h2
  float* buf1 = (float*)alloc((size_t)NN * D1 * 4);  // h1 -> xws2 -> h4
  float* buf2 = (float*)alloc((size_t)NN * D1 * 4);  // A1 -> A2|B2
  float* buf3 = (float*)alloc((size_t)NN * D1 * 4);  // B1 -> h3

  hipMemsetAsync(d_ws, 0xFF, ff_bytes, stream);
  hipMemsetAsync(ws + ff_bytes, 0, zero_end - ff_bytes, stream);

  // CSR build: packed LL exchange + single-walk convert (also emits dis, xs)
  k_build<<<cdiv(NE, 256), 256, 0, stream>>>(ei, adj, head_e, pack_e, head_a, pack_a);
  k_convert<<<cdiv(NN2, 256), 256, 0, stream>>>(head_e, pack_e, head_a, pack_a, x,
                                                deg_e, slot_e, deg_a, slot_a, dis, xs);

  // layer 1: GCN(9->64) + relu — gather in INPUT dim (linear), then GEMM epilogue
  k_gagg<<<cdiv(NN * (XSP / 4), 256), 256, 0, stream>>>(
      (const float4*)xs, deg_e, slot_e, (float4*)gbuf);
  k_gemm<FIN, D1, 2, false, XSP><<<cdiv(NN, 64), 256, 0, stream>>>(
      gbuf, W1, dis, b1, buf1, nullptr);

  // layer 2: EdgeConv(64->64)
  k_gemm<D1, 2 * D1, 1, false, D1><<<cdiv(NN, 32), 256, 0, stream>>>(
      buf1, eW1, nullptr, nullptr, buf2, buf3);
  k_edge4<D1><<<cdiv(NN * (D1 / 4), 256), 256, 0, stream>>>(
      (const float4*)buf2, (const float4*)buf3, eb1, deg_a, slot_a, (float4*)buf0);

  // layer 3: GCN(64->32) + relu — gather after GEMM (32-dim is the cheap side)
  k_gemm<D1, D2, 0, true, D1><<<cdiv(NN, 64), 256, 0, stream>>>(
      buf0, W2, dis, nullptr, buf1, nullptr);
  k_gcn4<D2><<<cdiv(NN * (D2 / 4), 256), 256, 0, stream>>>(
      (const float4*)buf1, dis, deg_e, slot_e, b2, (float4*)buf3);

  // layer 4: EdgeConv(32->32)
  float* A2 = buf2;
  float* B2 = buf2 + (size_t)NN * D2;
  k_gemm<D2, 2 * D2, 1, false, D2><<<cdiv(NN, 64), 256, 0, stream>>>(
      buf3, eW2, nullptr, nullptr, A2, B2);
  k_edge4<D2><<<cdiv(NN * (D2 / 4), 256), 256, 0, stream>>>(
      (const float4*)A2, (const float4*)B2, eb2, deg_a, slot_a, (float4*)buf1);

  // FC + mean pool
  k_final<<<cdiv(NN, 256), 256, 0, stream>>>(buf1, fcW, fcb, batch, sums, cnt);
  k_out<<<cdiv(NG, 256), 256, 0, stream>>>(sums, cnt, out);
}